// Round 5
// baseline (215.398 us; speedup 1.0000x reference)
//
#include <hip/hip_runtime.h>
#include <stdint.h>
#include <math.h>

// Problem constants (fixed by setup_inputs)
#define B_ROWS 16384
#define D_DIM  1024
#define OUT_N  4096

typedef __bf16 bf16x8 __attribute__((ext_vector_type(8)));
typedef float  f32x16 __attribute__((ext_vector_type(16)));

__device__ __forceinline__ unsigned short f2bf(float f) {
  union { float f; uint32_t u; } v; v.f = f;
  uint32_t u = v.u;
  u += 0x7FFFu + ((u >> 16) & 1u);   // round-to-nearest-even
  return (unsigned short)(u >> 16);
}

// ---------------- fused prep kernel ----------------
// blocks [0, B_ROWS): x rows -> xbf + beta
// blocks [B_ROWS, B_ROWS+OUT_N): z rows -> zbf + zp = {cosh/zn, sinh, zn, bias*log2e}
__global__ void prep_kernel(const float* __restrict__ x,
                            const float* __restrict__ z,
                            const float* __restrict__ r,
                            const float* __restrict__ bias,
                            unsigned short* __restrict__ xbf,
                            unsigned short* __restrict__ zbf,
                            float* __restrict__ beta,
                            float4* __restrict__ zp) {
  const int b = blockIdx.x;
  const int t = threadIdx.x;   // 256 threads, 4 floats each
  __shared__ float ws4[4];
  if (b < B_ROWS) {
    const int row = b;
    const float4 v = reinterpret_cast<const float4*>(x + (size_t)row * D_DIM)[t];
    float ssq = v.x * v.x + v.y * v.y + v.z * v.z + v.w * v.w;
    ushort4 h;
    h.x = f2bf(v.x); h.y = f2bf(v.y); h.z = f2bf(v.z); h.w = f2bf(v.w);
    reinterpret_cast<ushort4*>(xbf + (size_t)row * D_DIM)[t] = h;
#pragma unroll
    for (int off = 32; off > 0; off >>= 1) ssq += __shfl_down(ssq, off);
    if ((t & 63) == 0) ws4[t >> 6] = ssq;
    __syncthreads();
    if (t == 0) {
      float s = ws4[0] + ws4[1] + ws4[2] + ws4[3];
      beta[row] = sqrtf(1.0f + s);   // sqrt(1 - K*x^2), K = -1
    }
  } else {
    const int row = b - B_ROWS;
    const float4 v = reinterpret_cast<const float4*>(z + (size_t)row * D_DIM)[t];
    float ssq = v.x * v.x + v.y * v.y + v.z * v.z + v.w * v.w;
    ushort4 h;
    h.x = f2bf(v.x); h.y = f2bf(v.y); h.z = f2bf(v.z); h.w = f2bf(v.w);
    reinterpret_cast<ushort4*>(zbf + (size_t)row * D_DIM)[t] = h;
#pragma unroll
    for (int off = 32; off > 0; off >>= 1) ssq += __shfl_down(ssq, off);
    if ((t & 63) == 0) ws4[t >> 6] = ssq;
    __syncthreads();
    if (t == 0) {
      float s = ws4[0] + ws4[1] + ws4[2] + ws4[3];
      float zn = fmaxf(sqrtf(s), 1e-15f);
      float sr = fminf(fmaxf(r[row], -15.0f), 15.0f);
      float ch = coshf(sr), sh = sinhf(sr);
      const float LOG2E = 1.4426950408889634f;
      zp[row] = make_float4(ch / zn, sh, zn, bias[row] * LOG2E);
    }
  }
}

// ---------------- fused GEMM (256x256 8-phase, 32x32x16 MFMA) + epilogue ----------------

__device__ __forceinline__ void gload_lds16(const void* g, void* l) {
  __builtin_amdgcn_global_load_lds((__attribute__((address_space(1))) void*)g,
                                   (__attribute__((address_space(3))) void*)l,
                                   16, 0, 0);
}

#define FENCE() asm volatile("" ::: "memory")
#define BARRIER() do { FENCE(); __builtin_amdgcn_s_barrier(); FENCE(); } while (0)
#define WAITVM4() asm volatile("s_waitcnt vmcnt(4)" ::: "memory")
#define WAITVM0() asm volatile("s_waitcnt vmcnt(0)" ::: "memory")

// Stage one half-tile (128 rows x 64 cols bf16 = 16 KB) into LDS.
// Linear LDS dest; swizzle achieved by pre-swizzling the per-lane GLOBAL source
// (rule #21): logical 16B chunk q of row r lives at physical slot q ^ (r&7).
__device__ __forceinline__ void stage_half(const unsigned short* __restrict__ src,
                                           int grow0, int k0,
                                           unsigned short* ldsbase,
                                           int wave, int lane) {
#pragma unroll
  for (int j = 0; j < 2; ++j) {
    const int c = wave * 2 + j;                 // chunk 0..15, wave-uniform
    const int r = c * 8 + (lane >> 3);          // row within half
    const int col8 = (lane & 7) ^ (lane >> 3);  // inverse-swizzled source chunk
    gload_lds16(src + (size_t)(grow0 + r) * D_DIM + k0 + col8 * 8,
                ldsbase + c * 512);             // 1024 B per chunk
  }
}

// 32x32x16 A-operand: row = lane&31, k = (lane>>5)*8 + i  (8 consec bf16 -> b128)
__device__ __forceinline__ void load_a32(bf16x8 a[2][4], const unsigned short* Ab,
                                         int qm, int lane) {
  const int rl  = lane & 31;
  const int kh  = lane >> 5;
  const int key = lane & 7;        // = row&7 (qm*64, mi*32 are 0 mod 8)
#pragma unroll
  for (int mi = 0; mi < 2; ++mi) {
    const int row = qm * 64 + mi * 32 + rl;
#pragma unroll
    for (int ks = 0; ks < 4; ++ks)
      a[mi][ks] = *reinterpret_cast<const bf16x8*>(
          &Ab[row * 64 + ((ks * 2 + kh) ^ key) * 8]);
  }
}

// 32x32x16 B-operand: col = lane&31, same k split
__device__ __forceinline__ void load_b32(bf16x8 b[4], const unsigned short* Bb,
                                         int qn, int lane) {
  const int row = qn * 32 + (lane & 31);
  const int kh  = lane >> 5;
  const int key = lane & 7;
#pragma unroll
  for (int ks = 0; ks < 4; ++ks)
    b[ks] = *reinterpret_cast<const bf16x8*>(
        &Bb[row * 64 + ((ks * 2 + kh) ^ key) * 8]);
}

__device__ __forceinline__ void mma_quad32(f32x16 acc[4][2], const bf16x8 a[2][4],
                                           const bf16x8 b[4], int qm, int qn) {
  __builtin_amdgcn_s_setprio(1);
#pragma unroll
  for (int ks = 0; ks < 4; ++ks)
#pragma unroll
    for (int mi = 0; mi < 2; ++mi)
      acc[qm * 2 + mi][qn] = __builtin_amdgcn_mfma_f32_32x32x16_bf16(
          a[mi][ks], b[ks], acc[qm * 2 + mi][qn], 0, 0, 0);
  __builtin_amdgcn_s_setprio(0);
}

// LDS layout (ushort offsets): buf b: b*32768 | A: +0, B: +16384 | half h: +8192
__global__ __launch_bounds__(512) void gemm_fused(
    const unsigned short* __restrict__ xbf,
    const unsigned short* __restrict__ zbf,
    const float* __restrict__ beta,
    const float4* __restrict__ zp,
    float* __restrict__ out) {
  __shared__ unsigned short lds[65536];   // 128 KiB

  const int t = threadIdx.x;
  const int lane = t & 63;
  const int wave = t >> 6;
  const int wm = wave >> 2;      // 0..1
  const int wn = wave & 3;       // 0..3

  // XCD-aware mapping: XCD owns an 8-tile m-band (A 4 MB, L2-resident); m fast,
  // n slow (8 consecutive blocks share one B-tile). Bijective over 1024 blocks.
  const int bid = blockIdx.x;
  const int xcd = bid & 7;
  const int j   = bid >> 3;
  const int m0 = (xcd * 8 + (j & 7)) * 256;
  const int n0 = (j >> 3) * 256;

  unsigned short* A0 = lds + wm * 8192;                          // buf0.A (my half)
  unsigned short* A1 = lds + 32768 + wm * 8192;                  // buf1.A
  unsigned short* B0 = lds + 16384 + (wn >> 1) * 8192 + (wn & 1) * 4096;  // buf0.B (my 64 rows)
  unsigned short* B1 = B0 + 32768;                               // buf1.B

  f32x16 acc[4][2] = {};            // [Mi 0..3][Ni 0..1] 32x32 frags
  bf16x8 a[2][4], b0[4], b1[4];

  // ---- prologue: tile0 (buf0 full) + tile1 B (buf1.B); leave buf1.B in flight
  stage_half(xbf, m0,       0, lds,                 wave, lane);
  stage_half(xbf, m0 + 128, 0, lds + 8192,          wave, lane);
  stage_half(zbf, n0,       0, lds + 16384,         wave, lane);
  stage_half(zbf, n0 + 128, 0, lds + 16384 + 8192,  wave, lane);
  stage_half(zbf, n0,      64, lds + 32768 + 16384,        wave, lane);
  stage_half(zbf, n0 + 128,64, lds + 32768 + 16384 + 8192, wave, lane);
  WAITVM4();   // tile0 fully landed; tile1.B still in flight
  BARRIER();

#pragma unroll 1
  for (int i = 0; i < 8; ++i) {
    const int kA1 = (2 * i + 1) * 64;
    const int kT2 = (2 * i + 2) * 64;
    const int kT3 = (2 * i + 3) * 64;
    const bool more = (i < 7);

    // ---- P1: compute buf0 quad(0,0); stage buf1.A.h0
    load_a32(a, A0, 0, lane);
    load_b32(b0, B0, 0, lane);
    stage_half(xbf, m0, kA1, lds + 32768, wave, lane);
    BARRIER();
    mma_quad32(acc, a, b0, 0, 0);
    BARRIER();
    // ---- P2: quad(0,1); stage buf1.A.h1
    load_b32(b1, B0, 1, lane);
    stage_half(xbf, m0 + 128, kA1, lds + 32768 + 8192, wave, lane);
    BARRIER();
    mma_quad32(acc, a, b1, 0, 1);
    BARRIER();
    // ---- P3: quad(1,0); stage buf0.B.h0 (t2)
    load_a32(a, A0, 1, lane);
    if (more) stage_half(zbf, n0, kT2, lds + 16384, wave, lane);
    BARRIER();
    mma_quad32(acc, a, b0, 1, 0);
    BARRIER();
    // ---- P4: quad(1,1); stage buf0.B.h1 (t2); counted vmcnt
    if (more) stage_half(zbf, n0 + 128, kT2, lds + 16384 + 8192, wave, lane);
    BARRIER();
    mma_quad32(acc, a, b1, 1, 1);
    if (more) { WAITVM4(); } else { WAITVM0(); }
    BARRIER();

    // ---- P5: compute buf1 quad(0,0); stage buf0.A.h0 (t2)
    load_a32(a, A1, 0, lane);
    load_b32(b0, B1, 0, lane);
    if (more) stage_half(xbf, m0, kT2, lds, wave, lane);
    BARRIER();
    mma_quad32(acc, a, b0, 0, 0);
    BARRIER();
    // ---- P6: quad(0,1); stage buf0.A.h1 (t2)
    load_b32(b1, B1, 1, lane);
    if (more) stage_half(xbf, m0 + 128, kT2, lds + 8192, wave, lane);
    BARRIER();
    mma_quad32(acc, a, b1, 0, 1);
    BARRIER();
    // ---- P7: quad(1,0); stage buf1.B.h0 (t3)
    load_a32(a, A1, 1, lane);
    if (more) stage_half(zbf, n0, kT3, lds + 32768 + 16384, wave, lane);
    BARRIER();
    mma_quad32(acc, a, b0, 1, 0);
    BARRIER();
    // ---- P8: quad(1,1); stage buf1.B.h1 (t3); counted vmcnt
    if (more) stage_half(zbf, n0 + 128, kT3, lds + 32768 + 16384 + 8192, wave, lane);
    BARRIER();
    mma_quad32(acc, a, b1, 1, 1);
    if (more) WAITVM4();
    BARRIER();
  }

  // ---- epilogue: arg = (cosh/zn)*xz - sinh*beta;
  // y = sinh(zn*asinh(clip(arg)) + bias) = 0.5*(e - 1/e),
  // e = exp2( copysign(zn,arg)*log2(ax+sqrt(ax^2+1)) + bias*log2e )
  // 32x32 C/D layout: col = lane&31, row = (reg&3) + 8*(reg>>2) + 4*(lane>>5)
  const int hi   = lane >> 5;
  const int col0 = n0 + wn * 64 + (lane & 31);
  float4 pq[2];
#pragma unroll
  for (int ni = 0; ni < 2; ++ni) pq[ni] = zp[col0 + ni * 32];

#pragma unroll
  for (int Mi = 0; Mi < 4; ++Mi) {
#pragma unroll
    for (int q = 0; q < 4; ++q) {
      const int r0 = m0 + wm * 128 + Mi * 32 + q * 8 + hi * 4;
      const float4 b4 = *reinterpret_cast<const float4*>(&beta[r0]);
      const float btv[4] = {b4.x, b4.y, b4.z, b4.w};
#pragma unroll
      for (int jj = 0; jj < 4; ++jj) {
        const size_t rowbase = (size_t)(r0 + jj) * OUT_N + col0;
#pragma unroll
        for (int ni = 0; ni < 2; ++ni) {
          float acv = acc[Mi][ni][q * 4 + jj];
          float arg = fmaf(pq[ni].x, acv, -(pq[ni].y * btv[jj]));
          float ax  = fminf(fabsf(arg), 1e6f);
          float s   = __builtin_amdgcn_sqrtf(fmaf(ax, ax, 1.0f));
          float tl  = __builtin_amdgcn_logf(ax + s);          // log2
          float zs  = copysignf(pq[ni].z, arg);
          float e   = __builtin_amdgcn_exp2f(fmaf(zs, tl, pq[ni].w));
          float rc  = __builtin_amdgcn_rcpf(e);
          out[rowbase + ni * 32] = fmaf(-0.5f, rc, 0.5f * e);
        }
      }
    }
  }
}

// ---------------- launch ----------------

extern "C" void kernel_launch(void* const* d_in, const int* in_sizes, int n_in,
                              void* d_out, int out_size, void* d_ws, size_t ws_size,
                              hipStream_t stream) {
  const float* x    = (const float*)d_in[0];
  const float* z    = (const float*)d_in[1];
  const float* r    = (const float*)d_in[2];
  const float* bias = (const float*)d_in[3];
  float* out = (float*)d_out;

  char* ws = (char*)d_ws;
  unsigned short* xbf = (unsigned short*)ws;                               // 32 MB
  unsigned short* zbf = (unsigned short*)(ws + (size_t)32 * 1024 * 1024);  //  8 MB
  float* beta = (float*)(ws + (size_t)40 * 1024 * 1024);                   // 64 KB
  float4* zp  = (float4*)(ws + (size_t)40 * 1024 * 1024 + 64 * 1024);      // 64 KB

  prep_kernel<<<dim3(B_ROWS + OUT_N), dim3(256), 0, stream>>>(x, z, r, bias, xbf, zbf, beta, zp);
  gemm_fused<<<dim3((B_ROWS / 256) * (OUT_N / 256)), dim3(512), 0, stream>>>(
      xbf, zbf, beta, zp, out);
}

// Round 6
// 194.474 us; speedup vs baseline: 1.1076x; 1.1076x over previous
//
#include <hip/hip_runtime.h>
#include <stdint.h>
#include <math.h>

// Problem constants (fixed by setup_inputs)
#define B_ROWS 16384
#define D_DIM  1024
#define OUT_N  4096

typedef __bf16 bf16x8 __attribute__((ext_vector_type(8)));
typedef float  f32x4  __attribute__((ext_vector_type(4)));

__device__ __forceinline__ unsigned short f2bf(float f) {
  union { float f; uint32_t u; } v; v.f = f;
  uint32_t u = v.u;
  u += 0x7FFFu + ((u >> 16) & 1u);   // round-to-nearest-even
  return (unsigned short)(u >> 16);
}

// ---------------- fused prep kernel ----------------
// blocks [0, B_ROWS): x rows -> xbf + beta
// blocks [B_ROWS, B_ROWS+OUT_N): z rows -> zbf + zp = {cosh/zn, sinh, zn, bias*log2e}
__global__ void prep_kernel(const float* __restrict__ x,
                            const float* __restrict__ z,
                            const float* __restrict__ r,
                            const float* __restrict__ bias,
                            unsigned short* __restrict__ xbf,
                            unsigned short* __restrict__ zbf,
                            float* __restrict__ beta,
                            float4* __restrict__ zp) {
  const int b = blockIdx.x;
  const int t = threadIdx.x;   // 256 threads, 4 floats each
  __shared__ float ws4[4];
  if (b < B_ROWS) {
    const int row = b;
    const float4 v = reinterpret_cast<const float4*>(x + (size_t)row * D_DIM)[t];
    float ssq = v.x * v.x + v.y * v.y + v.z * v.z + v.w * v.w;
    ushort4 h;
    h.x = f2bf(v.x); h.y = f2bf(v.y); h.z = f2bf(v.z); h.w = f2bf(v.w);
    reinterpret_cast<ushort4*>(xbf + (size_t)row * D_DIM)[t] = h;
#pragma unroll
    for (int off = 32; off > 0; off >>= 1) ssq += __shfl_down(ssq, off);
    if ((t & 63) == 0) ws4[t >> 6] = ssq;
    __syncthreads();
    if (t == 0) {
      float s = ws4[0] + ws4[1] + ws4[2] + ws4[3];
      beta[row] = sqrtf(1.0f + s);   // sqrt(1 - K*x^2), K = -1
    }
  } else {
    const int row = b - B_ROWS;
    const float4 v = reinterpret_cast<const float4*>(z + (size_t)row * D_DIM)[t];
    float ssq = v.x * v.x + v.y * v.y + v.z * v.z + v.w * v.w;
    ushort4 h;
    h.x = f2bf(v.x); h.y = f2bf(v.y); h.z = f2bf(v.z); h.w = f2bf(v.w);
    reinterpret_cast<ushort4*>(zbf + (size_t)row * D_DIM)[t] = h;
#pragma unroll
    for (int off = 32; off > 0; off >>= 1) ssq += __shfl_down(ssq, off);
    if ((t & 63) == 0) ws4[t >> 6] = ssq;
    __syncthreads();
    if (t == 0) {
      float s = ws4[0] + ws4[1] + ws4[2] + ws4[3];
      float zn = fmaxf(sqrtf(s), 1e-15f);
      float sr = fminf(fmaxf(r[row], -15.0f), 15.0f);
      float ch = coshf(sr), sh = sinhf(sr);
      const float LOG2E = 1.4426950408889634f;
      zp[row] = make_float4(ch / zn, sh, zn, bias[row] * LOG2E);
    }
  }
}

// ---------------- fused GEMM (256x256 8-phase, 16x16x32 MFMA) + epilogue ----------------

__device__ __forceinline__ void gload_lds16(const void* g, void* l) {
  __builtin_amdgcn_global_load_lds((__attribute__((address_space(1))) void*)g,
                                   (__attribute__((address_space(3))) void*)l,
                                   16, 0, 0);
}

#define FENCE() asm volatile("" ::: "memory")
#define BARRIER() do { FENCE(); __builtin_amdgcn_s_barrier(); FENCE(); } while (0)
#define WAITVM4() asm volatile("s_waitcnt vmcnt(4)" ::: "memory")
#define WAITVM0() asm volatile("s_waitcnt vmcnt(0)" ::: "memory")

// Stage one half-tile (128 rows x 64 cols bf16 = 16 KB) into LDS.
// Linear LDS dest; swizzle achieved by pre-swizzling the per-lane GLOBAL source
// (rule #21): logical 16B chunk q of row r lives at physical slot q ^ (r&7).
__device__ __forceinline__ void stage_half(const unsigned short* __restrict__ src,
                                           int grow0, int k0,
                                           unsigned short* ldsbase,
                                           int wave, int lane) {
#pragma unroll
  for (int j = 0; j < 2; ++j) {
    const int c = wave * 2 + j;                 // chunk 0..15, wave-uniform
    const int r = c * 8 + (lane >> 3);          // row within half
    const int col8 = (lane & 7) ^ (lane >> 3);  // inverse-swizzled source chunk
    gload_lds16(src + (size_t)(grow0 + r) * D_DIM + k0 + col8 * 8,
                ldsbase + c * 512);             // 1024 B per chunk
  }
}

__device__ __forceinline__ void load_a(bf16x8 a[4][2], const unsigned short* Ab,
                                       int qm, int lrow, int lgrp) {
  const int key = lrow & 7;
#pragma unroll
  for (int mi = 0; mi < 4; ++mi)
#pragma unroll
    for (int ks = 0; ks < 2; ++ks)
      a[mi][ks] = *reinterpret_cast<const bf16x8*>(
          &Ab[(qm * 64 + mi * 16 + lrow) * 64 + ((ks * 4 + lgrp) ^ key) * 8]);
}

__device__ __forceinline__ void load_b(bf16x8 b[2][2], const unsigned short* Bb,
                                       int qn, int lrow, int lgrp) {
  const int key = lrow & 7;
#pragma unroll
  for (int ni = 0; ni < 2; ++ni)
#pragma unroll
    for (int ks = 0; ks < 2; ++ks)
      b[ni][ks] = *reinterpret_cast<const bf16x8*>(
          &Bb[(qn * 32 + ni * 16 + lrow) * 64 + ((ks * 4 + lgrp) ^ key) * 8]);
}

__device__ __forceinline__ void mma_quad(f32x4 acc[8][4], const bf16x8 a[4][2],
                                         const bf16x8 b[2][2], int qm, int qn) {
  __builtin_amdgcn_s_setprio(1);
#pragma unroll
  for (int mi = 0; mi < 4; ++mi)
#pragma unroll
    for (int ni = 0; ni < 2; ++ni)
#pragma unroll
      for (int ks = 0; ks < 2; ++ks)
        acc[qm * 4 + mi][qn * 2 + ni] = __builtin_amdgcn_mfma_f32_16x16x32_bf16(
            a[mi][ks], b[ni][ks], acc[qm * 4 + mi][qn * 2 + ni], 0, 0, 0);
  __builtin_amdgcn_s_setprio(0);
}

// LDS layout (ushort offsets): buf b: b*32768 | A: +0, B: +16384 | half h: +8192
// within half: row r (0..127): r*64, 16B chunk c: c*8 (physical, swizzled)
__global__ __launch_bounds__(512) void gemm_fused(
    const unsigned short* __restrict__ xbf,
    const unsigned short* __restrict__ zbf,
    const float* __restrict__ beta,
    const float4* __restrict__ zp,
    float* __restrict__ out) {
  __shared__ unsigned short lds[65536];   // 128 KiB

  const int t = threadIdx.x;
  const int lane = t & 63;
  const int wave = t >> 6;
  const int wm = wave >> 2;      // 0..1
  const int wn = wave & 3;       // 0..3
  const int lrow = lane & 15;
  const int lgrp = lane >> 4;

  // XCD-aware mapping: XCD owns an 8-tile m-band (A 4 MB, L2-resident); m fast,
  // n slow (8 consecutive blocks share one B-tile). Bijective over 1024 blocks.
  const int bid = blockIdx.x;
  const int xcd = bid & 7;
  const int j   = bid >> 3;
  const int m0 = (xcd * 8 + (j & 7)) * 256;
  const int n0 = (j >> 3) * 256;

  unsigned short* A0 = lds + wm * 8192;                          // buf0.A (my half)
  unsigned short* A1 = lds + 32768 + wm * 8192;                  // buf1.A
  unsigned short* B0 = lds + 16384 + (wn >> 1) * 8192 + (wn & 1) * 4096;  // buf0.B (my 64 rows)
  unsigned short* B1 = B0 + 32768;                               // buf1.B

  f32x4 acc[8][4] = {};
  bf16x8 a[4][2], b0[2][2], b1[2][2];

  // ---- prologue: tile0 (buf0 full) + tile1 B (buf1.B); leave buf1.B in flight
  stage_half(xbf, m0,       0, lds,                 wave, lane);
  stage_half(xbf, m0 + 128, 0, lds + 8192,          wave, lane);
  stage_half(zbf, n0,       0, lds + 16384,         wave, lane);
  stage_half(zbf, n0 + 128, 0, lds + 16384 + 8192,  wave, lane);
  stage_half(zbf, n0,      64, lds + 32768 + 16384,        wave, lane);
  stage_half(zbf, n0 + 128,64, lds + 32768 + 16384 + 8192, wave, lane);
  WAITVM4();   // tile0 fully landed; tile1.B still in flight
  BARRIER();

#pragma unroll 1
  for (int i = 0; i < 8; ++i) {
    const int kA1 = (2 * i + 1) * 64;   // odd tile this iteration (buf1)
    const int kT2 = (2 * i + 2) * 64;   // next even tile (buf0)
    const int kT3 = (2 * i + 3) * 64;   // next odd tile (buf1)
    const bool more = (i < 7);

    // ---- P1: compute buf0 quad(0,0); stage buf1.A.h0 (tile 2i+1)
    load_a(a, A0, 0, lrow, lgrp);
    load_b(b0, B0, 0, lrow, lgrp);
    stage_half(xbf, m0, kA1, lds + 32768, wave, lane);
    BARRIER();
    mma_quad(acc, a, b0, 0, 0);
    BARRIER();
    // ---- P2: quad(0,1); stage buf1.A.h1
    load_b(b1, B0, 1, lrow, lgrp);
    stage_half(xbf, m0 + 128, kA1, lds + 32768 + 8192, wave, lane);
    BARRIER();
    mma_quad(acc, a, b1, 0, 1);
    BARRIER();
    // ---- P3: quad(1,0); stage buf0.B.h0 (tile 2i+2)
    load_a(a, A0, 1, lrow, lgrp);
    if (more) stage_half(zbf, n0, kT2, lds + 16384, wave, lane);
    BARRIER();
    mma_quad(acc, a, b0, 1, 0);
    BARRIER();
    // ---- P4: quad(1,1); stage buf0.B.h1; counted vmcnt
    if (more) stage_half(zbf, n0 + 128, kT2, lds + 16384 + 8192, wave, lane);
    BARRIER();
    mma_quad(acc, a, b1, 1, 1);
    if (more) { WAITVM4(); } else { WAITVM0(); }
    BARRIER();

    // ---- P5: compute buf1 quad(0,0); stage buf0.A.h0 (tile 2i+2)
    load_a(a, A1, 0, lrow, lgrp);
    load_b(b0, B1, 0, lrow, lgrp);
    if (more) stage_half(xbf, m0, kT2, lds, wave, lane);
    BARRIER();
    mma_quad(acc, a, b0, 0, 0);
    BARRIER();
    // ---- P6: quad(0,1); stage buf0.A.h1
    load_b(b1, B1, 1, lrow, lgrp);
    if (more) stage_half(xbf, m0 + 128, kT2, lds + 8192, wave, lane);
    BARRIER();
    mma_quad(acc, a, b1, 0, 1);
    BARRIER();
    // ---- P7: quad(1,0); stage buf1.B.h0 (tile 2i+3)
    load_a(a, A1, 1, lrow, lgrp);
    if (more) stage_half(zbf, n0, kT3, lds + 32768 + 16384, wave, lane);
    BARRIER();
    mma_quad(acc, a, b0, 1, 0);
    BARRIER();
    // ---- P8: quad(1,1); stage buf1.B.h1; counted vmcnt
    if (more) stage_half(zbf, n0 + 128, kT3, lds + 32768 + 16384 + 8192, wave, lane);
    BARRIER();
    mma_quad(acc, a, b1, 1, 1);
    if (more) WAITVM4();
    BARRIER();
  }

  // ---- epilogue: arg = (cosh/zn)*xz - sinh*beta;
  // y = sinh(zn*asinh(clip(arg)) + bias) = 0.5*(e - 1/e),
  // e = exp2( copysign(zn,arg)*log2(ax+sqrt(ax^2+1)) + bias*log2e )
  // ni-innermost store order: full 256B row segments -> no write amplification.
  float4 pq[4];
#pragma unroll
  for (int ni = 0; ni < 4; ++ni) pq[ni] = zp[n0 + wn * 64 + ni * 16 + lrow];
  const int ocol0 = n0 + wn * 64 + lrow;

#pragma unroll
  for (int mi = 0; mi < 8; ++mi) {
    const int r0 = m0 + wm * 128 + mi * 16 + lgrp * 4;
    const float4 b4 = *reinterpret_cast<const float4*>(&beta[r0]);
    const float btv[4] = {b4.x, b4.y, b4.z, b4.w};
#pragma unroll
    for (int jj = 0; jj < 4; ++jj) {
      const size_t rowbase = (size_t)(r0 + jj) * OUT_N + ocol0;
#pragma unroll
      for (int ni = 0; ni < 4; ++ni) {
        float acv = acc[mi][ni][jj];
        float arg = fmaf(pq[ni].x, acv, -(pq[ni].y * btv[jj]));
        float ax  = fminf(fabsf(arg), 1e6f);
        float s   = __builtin_amdgcn_sqrtf(fmaf(ax, ax, 1.0f));
        float tl  = __builtin_amdgcn_logf(ax + s);          // log2(ax + sqrt(ax^2+1))
        float zs  = copysignf(pq[ni].z, arg);
        float e   = __builtin_amdgcn_exp2f(fmaf(zs, tl, pq[ni].w));
        float rc  = __builtin_amdgcn_rcpf(e);
        out[rowbase + ni * 16] = fmaf(-0.5f, rc, 0.5f * e);
      }
    }
  }
}

// ---------------- launch ----------------

extern "C" void kernel_launch(void* const* d_in, const int* in_sizes, int n_in,
                              void* d_out, int out_size, void* d_ws, size_t ws_size,
                              hipStream_t stream) {
  const float* x    = (const float*)d_in[0];
  const float* z    = (const float*)d_in[1];
  const float* r    = (const float*)d_in[2];
  const float* bias = (const float*)d_in[3];
  float* out = (float*)d_out;

  char* ws = (char*)d_ws;
  unsigned short* xbf = (unsigned short*)ws;                               // 32 MB
  unsigned short* zbf = (unsigned short*)(ws + (size_t)32 * 1024 * 1024);  //  8 MB
  float* beta = (float*)(ws + (size_t)40 * 1024 * 1024);                   // 64 KB
  float4* zp  = (float4*)(ws + (size_t)40 * 1024 * 1024 + 64 * 1024);      // 64 KB

  prep_kernel<<<dim3(B_ROWS + OUT_N), dim3(256), 0, stream>>>(x, z, r, bias, xbf, zbf, beta, zp);
  gemm_fused<<<dim3((B_ROWS / 256) * (OUT_N / 256)), dim3(512), 0, stream>>>(
      xbf, zbf, beta, zp, out);
}